// Round 22
// baseline (62.352 us; speedup 1.0000x reference)
//
#include <hip/hip_runtime.h>
#include <hip/hip_bf16.h>

// Problem: B=4, S=128, H=768, OUT*TAG=96
// scores[b,i,j,o] = sum_k relu(head[b,i,k] + tail[b,j,k] + b1[k]) * W2[k,o] + b2[o]
// R21: k_pair = 32x32x16 f16 frags (W2 LDS reads halved), in-block K-split
//      (4 waves = 2 K-half x 2 i-slot), K-step 32, ring-3 (48KB) depth-2
//      stage-after-barrier, staged tail, vmcnt(12), conflict-free reduction.

typedef __bf16 bf16x8 __attribute__((ext_vector_type(8)));
typedef _Float16 f16x8 __attribute__((ext_vector_type(8)));
typedef float f32x4 __attribute__((ext_vector_type(4)));
typedef float f32x16 __attribute__((ext_vector_type(16)));

#define S_   128
#define H_   768
#define K3   2304   // 3*H
#define NOUT 96
#define NITG 36     // K-step-32 iterations per K-half (72 chunks / 2)

__device__ __forceinline__ unsigned short f2bf(float f) {
    union { __bf16 b; unsigned short u; } c;
    c.b = (__bf16)f;   // RNE
    return c.u;
}

__device__ __forceinline__ unsigned short f2h(float f) {
    union { _Float16 h; unsigned short u; } c;
    c.h = (_Float16)f;
    return c.u;
}

__device__ __forceinline__ void gload_lds16(const unsigned short* g, unsigned short* l) {
    __builtin_amdgcn_global_load_lds(
        (const __attribute__((address_space(1))) void*)g,
        (__attribute__((address_space(3))) void*)l,
        16, 0, 0);
}

// ---------- fused prep: cvt_x | transpose W1 | pack W2 (role by blockIdx.x) ----------
// W2 packed in 32x32-frag order [144 slices][3 og][64 l][8] (R17-verified):
//   elem(s,og,l,e) = W2[s*16 + (l>>5)*8 + e][og*32 + (l&31)]
__global__ __launch_bounds__(256) void k_prep(
        const float* __restrict__ x, unsigned short* __restrict__ xb,
        const float* __restrict__ W1, unsigned short* __restrict__ w1t,
        const float* __restrict__ W2, unsigned short* __restrict__ w2f) {
    __shared__ float tile[32][33];
    const int bid = blockIdx.x, tid = threadIdx.x;
    if (bid < 384) {
        int t = bid * 256 + tid;
        float4 v = ((const float4*)x)[t];
        ushort4 o;
        o.x = f2bf(v.x); o.y = f2bf(v.y); o.z = f2bf(v.z); o.w = f2bf(v.w);
        ((ushort4*)xb)[t] = o;
    } else if (bid < 3840) {
        int idx = bid - 384;
        int bx = idx % 72, by = (idx / 72) % 24, bz = idx / 1728;   // 72 x 24 x 2
        const float* src = W1 + (size_t)bz * H_ * K3;
        unsigned short* dst = w1t + (size_t)bz * K3 * H_;
        int c0 = bx * 32, r0 = by * 32;
        int row = tid >> 3, c4 = (tid & 7) * 4;
        float4 v = *(const float4*)(src + (size_t)(r0 + row) * K3 + c0 + c4);
        tile[row][c4 + 0] = v.x; tile[row][c4 + 1] = v.y;
        tile[row][c4 + 2] = v.z; tile[row][c4 + 3] = v.w;
        __syncthreads();
        ushort4 o;
        o.x = f2bf(tile[c4 + 0][row]); o.y = f2bf(tile[c4 + 1][row]);
        o.z = f2bf(tile[c4 + 2][row]); o.w = f2bf(tile[c4 + 3][row]);
        *(ushort4*)(dst + (size_t)(c0 + row) * H_ + r0 + c4) = o;
    } else {
        int t = (bid - 3840) * 256 + tid;   // 27648 exact = 144*3*64
        int l = t & 63, og = (t >> 6) % 3, s = t / 192;
        int k0 = s * 16 + (l >> 5) * 8;
        int o  = og * 32 + (l & 31);
        unsigned short v[8];
#pragma unroll
        for (int e = 0; e < 8; e++)
            v[e] = f2h(W2[(size_t)(k0 + e) * NOUT + o]);
        *(uint4*)(w2f + (size_t)t * 8) = *(const uint4*)v;
    }
}

// ---------- GEMM1 (R19-proven pipeline): 64x128 tiles, ring-3 counted-vmcnt ----------
// head -> headh row-major f16; tail+b1 -> tailsw [16 jbg][72 chunk32][4 u][32 row][8 e]
__global__ __launch_bounds__(256) void k_gemm1(
        const unsigned short* __restrict__ xb,     // [512][768] bf16
        const unsigned short* __restrict__ w1t,    // [4608][768] bf16
        const float* __restrict__ b1,              // [2304]
        unsigned short* __restrict__ headh,        // [512][2304] f16
        unsigned short* __restrict__ tailsw) {     // chunked tail, f16
    __shared__ __align__(16) unsigned short AB[3][6144];   // ring-3 {A 4KB | B 8KB}
    const int tid = threadIdx.x;
    const int l = tid & 63, w = tid >> 6;
    const int m0 = blockIdx.y * 64;
    const int n0 = blockIdx.x * 128;
    const int wr = (w >> 1) * 32, wc = (w & 1) * 64;
    const int lr = l & 15, lk = (l >> 4) * 8;
    f32x4 acc[2][4] = {};
    const int NKT = H_ / 32;   // 24

    auto stage = [&](int sbuf, int kt) {
        {
            int row = tid >> 2, seg = (tid & 3) * 8;
            gload_lds16(xb + (size_t)(m0 + row) * H_ + kt * 32 + seg, &AB[sbuf][tid * 8]);
        }
#pragma unroll
        for (int p = 0; p < 2; ++p) {
            int idx = p * 256 + tid;
            int row = idx >> 2, seg = (idx & 3) * 8;
            gload_lds16(w1t + (size_t)(n0 + row) * H_ + kt * 32 + seg,
                        &AB[sbuf][2048 + idx * 8]);
        }
    };

    stage(0, 0);
    stage(1, 1);

    for (int n = 0; n < NKT; ++n) {
        asm volatile("s_waitcnt vmcnt(3)" ::: "memory");
        __builtin_amdgcn_s_barrier();
        stage((n + 2) % 3, (n + 2 < NKT) ? (n + 2) : (NKT - 1));

        const unsigned short* Ab = &AB[n % 3][0];
        const unsigned short* Bb = &AB[n % 3][2048];
        bf16x8 af[2], bfr[4];
#pragma unroll
        for (int i = 0; i < 2; i++) af[i]  = *(const bf16x8*)(Ab + (wr + i * 16 + lr) * 32 + lk);
#pragma unroll
        for (int j = 0; j < 4; j++) bfr[j] = *(const bf16x8*)(Bb + (wc + j * 16 + lr) * 32 + lk);
#pragma unroll
        for (int i = 0; i < 2; i++)
#pragma unroll
            for (int j = 0; j < 4; j++)
                acc[i][j] = __builtin_amdgcn_mfma_f32_16x16x32_bf16(af[i], bfr[j], acc[i][j], 0, 0, 0);
    }

    const bool tailblk = (n0 >= K3);
    const int nloc = n0 - (tailblk ? K3 : 0);
    const int lv = (l >> 4) * 4;
    if (!tailblk) {
#pragma unroll
        for (int j = 0; j < 4; j++) {
            int c = nloc + wc + j * 16 + lr;
#pragma unroll
            for (int i = 0; i < 2; i++) {
                int mrow = m0 + wr + i * 16 + lv;
#pragma unroll
                for (int e = 0; e < 4; e++)
                    headh[(size_t)(mrow + e) * K3 + c] = f2h(acc[i][j][e]);
            }
        }
    } else {
#pragma unroll
        for (int j = 0; j < 4; j++) {
            int c = nloc + wc + j * 16 + lr;
            float bias = b1[c];
            int chunk = c >> 5, kin = c & 31, u = kin >> 3, ee = kin & 7;
#pragma unroll
            for (int i = 0; i < 2; i++) {
                int mrow = m0 + wr + i * 16 + lv;
#pragma unroll
                for (int e = 0; e < 4; e++) {
                    int r = mrow + e;                    // global row 0..511
                    int jbg = r >> 5, rr = r & 31;
                    size_t idx = (((size_t)(jbg * 72 + chunk) * 4 + u) * 32 + rr) * 8 + ee;
                    tailsw[idx] = f2h(acc[i][j][e] + bias);
                }
            }
        }
    }
}

// ---------- main pair kernel: 32x32x16, K-split, ring-3, staged tail ----------
// 256 thr = 4 waves: w -> (g = w>>1 : K-half, wi = w&1 : i-slot). Wave = 2i x 32j
// over chunks32 [36g, 36g+36). Per iter: ht(n+1)[4] -> vmcnt(12) -> barrier ->
// stage(n+2)[4 per-wave-uniform DMA ops] -> 8 ds_reads + 4 forms + 12 MFMA.
// Epilogue: g1 -> LDS (float4[24][128], conflict-free) -> g0 adds + writes.
__device__ __forceinline__ f16x8 form8t(uint4 hq, f16x8 t) {
    union { uint4 q; f16x8 v; } H;
    H.q = hq;
    f16x8 s = H.v + t;
    const f16x8 z = {0, 0, 0, 0, 0, 0, 0, 0};
    return __builtin_elementwise_max(s, z);
}

__global__ __launch_bounds__(256) void k_pair(
        const unsigned short* __restrict__ headh,  // [512][2304] f16
        const unsigned short* __restrict__ tailsw, // [16][72][4][32][8] f16
        const unsigned short* __restrict__ w2f,    // [144][3][64][8] f16 frag order
        const float* __restrict__ b2,              // [96]
        float* __restrict__ out) {                 // [4][128][128][96] fp32
    // 49,152 B shared: W2 ring wlds[2 half][3 ring][3072] + tail tlds[2][3][1024];
    // reused as float4 red[24][128] for the K-split reduction.
    __shared__ __align__(16) unsigned short smem[24576];

    const int tid = threadIdx.x;
    const int w = tid >> 6, l = tid & 63;
    const int g  = w >> 1;          // K-half
    const int wi = w & 1;           // i-slot
    const int p  = w & 1;           // staging portion (= wi)
    const int lo = l & 31;          // j (and o) sub-index
    const int kq = l >> 5;          // k half-slice
    const int ko = kq * 8;
    const int jb = blockIdx.x;      // 0..3   (32-j groups)
    const int ig = blockIdx.y;      // 0..31  (4-i groups)
    const int b  = blockIdx.z;      // 0..3
    const int i0 = ig * 4 + wi * 2;
    const int cbase = g * NITG;     // chunk32 base

    const unsigned short* Hp   = headh + (size_t)(b * S_ + i0) * K3;
    const unsigned short* Tsrc = tailsw + (size_t)(b * 4 + jb) * 72 * 1024;

    f32x16 acc[2][3] = {};   // [qi][og]

    // wave-uniform staging of chunk32 n (clamped) for BOTH halves:
    // wave w stages half g's buffers only (2 waves per half, portion p).
    auto stage = [&](int sbuf, int n) {
        const int cc = g * NITG + n;
        const unsigned short* wsrc = w2f + (size_t)cc * 3072;
        unsigned short* wdst = &smem[(g * 3 + sbuf) * 3072];
#pragma unroll
        for (int i = 0; i < 3; ++i)
            gload_lds16(wsrc + (p * 3 + i) * 512 + l * 8, wdst + (p * 3 + i) * 512 + l * 8);
        const unsigned short* tsrc = Tsrc + (size_t)cc * 1024;
        unsigned short* tdst = &smem[18432 + (g * 3 + sbuf) * 1024];
        gload_lds16(tsrc + p * 512 + l * 8, tdst + p * 512 + l * 8);
    };

    stage(0, 0);
    stage(1, 1);
    // head(0): 4 broadcast loads (2 si x 2 qi)
    uint4 hc[2][2], hn[2][2];   // [qi][si]
#pragma unroll
    for (int si = 0; si < 2; si++) {
        const int kb = cbase * 32 + si * 16 + ko;
        hc[0][si] = *(const uint4*)(Hp + kb);
        hc[1][si] = *(const uint4*)(Hp + K3 + kb);
    }

    for (int n = 0; n < NITG; ++n) {
        // head(n+1) prefetch [4 loads; clamped]
        const int cn = (n < NITG - 1) ? n + 1 : n;
        const int kbn = (cbase + cn) * 32;
#pragma unroll
        for (int si = 0; si < 2; si++) {
            hn[0][si] = *(const uint4*)(Hp + kbn + si * 16 + ko);
            hn[1][si] = *(const uint4*)(Hp + K3 + kbn + si * 16 + ko);
        }

        // younger-than-stage(n) = ht(n)[4] + stage(n+1)[4] + ht(n+1)[4] = 12.
        asm volatile("s_waitcnt vmcnt(12)" ::: "memory");
        __builtin_amdgcn_s_barrier();

        // depth-2 stage after barrier: buf (n+2)%3 = (n-1)%3, whose readers
        // (compute n-1) retired their ds_reads before reaching this barrier.
        stage((n + 2) % 3, (n + 2 < NITG) ? (n + 2) : (NITG - 1));

        const unsigned short* Lb = &smem[(g * 3 + n % 3) * 3072];
        const unsigned short* Tb = &smem[18432 + (g * 3 + n % 3) * 1024];
        __builtin_amdgcn_s_setprio(1);
#pragma unroll
        for (int si = 0; si < 2; si++) {
            f16x8 t8 = *(const f16x8*)(Tb + ((si * 2 + kq) * 32 + lo) * 8);
            f16x8 a0 = form8t(hc[0][si], t8);
            f16x8 a1 = form8t(hc[1][si], t8);
#pragma unroll
            for (int og = 0; og < 3; og++) {
                f16x8 bfr = *(const f16x8*)(Lb + ((si * 3 + og) * 64 + l) * 8);
                acc[0][og] = __builtin_amdgcn_mfma_f32_32x32x16_f16(a0, bfr, acc[0][og], 0, 0, 0);
                acc[1][og] = __builtin_amdgcn_mfma_f32_32x32x16_f16(a1, bfr, acc[1][og], 0, 0, 0);
            }
        }
        __builtin_amdgcn_s_setprio(0);
#pragma unroll
        for (int si = 0; si < 2; si++) { hc[0][si] = hn[0][si]; hc[1][si] = hn[1][si]; }
    }

    // ---- K-split reduction: drain dummy-stage DMA, then g1 -> LDS -> g0 adds ----
    asm volatile("s_waitcnt vmcnt(0)" ::: "memory");
    __syncthreads();
    float4* red = (float4*)&smem[0];   // [24 slots][128 lanes] = 49,152 B exact
    const int lid = wi * 64 + l;
    if (g == 1) {
#pragma unroll
        for (int qi = 0; qi < 2; qi++)
#pragma unroll
            for (int og = 0; og < 3; og++)
#pragma unroll
                for (int pp = 0; pp < 4; pp++)
                    red[((qi * 3 + og) * 4 + pp) * 128 + lid] =
                        make_float4(acc[qi][og][pp * 4 + 0], acc[qi][og][pp * 4 + 1],
                                    acc[qi][og][pp * 4 + 2], acc[qi][og][pp * 4 + 3]);
    }
    __syncthreads();
    if (g == 0) {
        float b2v[3];
#pragma unroll
        for (int og = 0; og < 3; og++) b2v[og] = b2[og * 32 + lo];
#pragma unroll
        for (int qi = 0; qi < 2; qi++)
#pragma unroll
            for (int og = 0; og < 3; og++)
#pragma unroll
                for (int pp = 0; pp < 4; pp++) {
                    float4 v = red[((qi * 3 + og) * 4 + pp) * 128 + lid];
                    acc[qi][og][pp * 4 + 0] += v.x; acc[qi][og][pp * 4 + 1] += v.y;
                    acc[qi][og][pp * 4 + 2] += v.z; acc[qi][og][pp * 4 + 3] += v.w;
                }
        // C/D 32x32 layout (R17-verified): col = og*32+lo, row j = (r&3)+8*(r>>2)+4*kq
#pragma unroll
        for (int qi = 0; qi < 2; qi++) {
            float* O = out + ((size_t)(b * S_ + i0 + qi) * S_ + jb * 32) * NOUT + lo;
#pragma unroll
            for (int og = 0; og < 3; og++)
#pragma unroll
                for (int r = 0; r < 16; r++) {
                    int j = (r & 3) + 8 * (r >> 2) + 4 * kq;
                    O[(size_t)j * NOUT + og * 32] = acc[qi][og][r] + b2v[og];
                }
        }
    }
}

extern "C" void kernel_launch(void* const* d_in, const int* in_sizes, int n_in,
                              void* d_out, int out_size, void* d_ws, size_t ws_size,
                              hipStream_t stream) {
    const float* x  = (const float*)d_in[0];   // [4][128][768]
    const float* W1 = (const float*)d_in[1];   // [1536][2304]
    const float* b1 = (const float*)d_in[2];   // [2304]
    const float* W2 = (const float*)d_in[3];   // [2304][96]
    const float* b2 = (const float*)d_in[4];   // [96]
    float* out = (float*)d_out;

    char* ws = (char*)d_ws;
    unsigned short* xb     = (unsigned short*)(ws);              //  512*768   bf16
    unsigned short* w1t    = (unsigned short*)(ws +   786432);   // 4608*768   bf16
    unsigned short* w2f    = (unsigned short*)(ws +  7864320);   //  144*3*64*8 f16
    unsigned short* headh  = (unsigned short*)(ws +  8306688);   //  512*2304  f16
    unsigned short* tailsw = (unsigned short*)(ws + 10665984);   //  16*72*1024 f16 (2.36MB)
    // total ws use: 13,025,280 bytes

    hipLaunchKernelGGL(k_prep, dim3(3948), dim3(256), 0, stream,
                       x, xb, W1, w1t, W2, w2f);
    hipLaunchKernelGGL(k_gemm1, dim3(36, 8), dim3(256), 0, stream,
                       xb, w1t, b1, headh, tailsw);
    hipLaunchKernelGGL(k_pair, dim3(4, 32, 4), dim3(256), 0, stream,
                       headh, tailsw, w2f, b2, out);
}

// Round 23
// 61.139 us; speedup vs baseline: 1.0198x; 1.0198x over previous
//
#include <hip/hip_runtime.h>
#include <hip/hip_bf16.h>

// Problem: B=4, S=128, H=768, OUT*TAG=96
// scores[b,i,j,o] = sum_k relu(head[b,i,k] + tail[b,j,k] + b1[k]) * W2[k,o] + b2[o]
// R22: k_pair = R20-verbatim (best, 43.1us). gemm1 retiled 64x64 (576 blocks,
//      better CU balance, 2-op staging, vmcnt(2)). W1-transpose retiled 64x64
//      (864 blocks, own kernel); x-convert + W2-pack fused (492 blocks).

typedef __bf16 bf16x8 __attribute__((ext_vector_type(8)));
typedef _Float16 f16x8 __attribute__((ext_vector_type(8)));
typedef float f32x4 __attribute__((ext_vector_type(4)));

#define S_   128
#define H_   768
#define K3   2304   // 3*H
#define NOUT 96
#define NIT  36     // K-step-64 iterations

__device__ __forceinline__ unsigned short f2bf(float f) {
    union { __bf16 b; unsigned short u; } c;
    c.b = (__bf16)f;   // RNE
    return c.u;
}

__device__ __forceinline__ unsigned short f2h(float f) {
    union { _Float16 h; unsigned short u; } c;
    c.h = (_Float16)f;
    return c.u;
}

__device__ __forceinline__ void gload_lds16(const unsigned short* g, unsigned short* l) {
    __builtin_amdgcn_global_load_lds(
        (const __attribute__((address_space(1))) void*)g,
        (__attribute__((address_space(3))) void*)l,
        16, 0, 0);
}

// ---------- prep A: x fp32->bf16 (384 blocks) | W2 pack (108 blocks) ----------
__global__ __launch_bounds__(256) void k_prep_xw2(
        const float* __restrict__ x, unsigned short* __restrict__ xb,
        const float* __restrict__ W2, unsigned short* __restrict__ w2f) {
    const int bid = blockIdx.x, tid = threadIdx.x;
    if (bid < 384) {
        int t = bid * 256 + tid;
        float4 v = ((const float4*)x)[t];
        ushort4 o;
        o.x = f2bf(v.x); o.y = f2bf(v.y); o.z = f2bf(v.z); o.w = f2bf(v.w);
        ((ushort4*)xb)[t] = o;
    } else {
        int t = (bid - 384) * 256 + tid;   // 27648 exact
        int l = t & 63, f = (t >> 6) % 6, kc = t / 384;
        int k0 = kc * 32 + (l >> 4) * 8;
        int o  = f * 16 + (l & 15);
        unsigned short v[8];
#pragma unroll
        for (int e = 0; e < 8; e++)
            v[e] = f2h(W2[(size_t)(k0 + e) * NOUT + o]);
        *(uint4*)(w2f + (size_t)t * 8) = *(const uint4*)v;
    }
}

// ---------- prep B: W1 transpose, 64x64 tiles (864 blocks) ----------
// w1t[bz*2304 + c][h] = W1[bz*768 + h][c]
__global__ __launch_bounds__(256) void k_prep_w1(
        const float* __restrict__ W1, unsigned short* __restrict__ w1t) {
    __shared__ float tile[64][65];
    const int idx = blockIdx.x, tid = threadIdx.x;
    int bx = idx % 36, by = (idx / 36) % 12, bz = idx / 432;   // 36 x 12 x 2
    const float* src = W1 + (size_t)bz * H_ * K3;
    unsigned short* dst = w1t + (size_t)bz * K3 * H_;
    int c0 = bx * 64, r0 = by * 64;
    int row = tid >> 2, cs = (tid & 3) * 16;
#pragma unroll
    for (int i = 0; i < 4; i++) {
        float4 v = *(const float4*)(src + (size_t)(r0 + row) * K3 + c0 + cs + i * 4);
        tile[row][cs + i * 4 + 0] = v.x; tile[row][cs + i * 4 + 1] = v.y;
        tile[row][cs + i * 4 + 2] = v.z; tile[row][cs + i * 4 + 3] = v.w;
    }
    __syncthreads();
    int c = tid >> 2, rs = (tid & 3) * 16;   // out row c, 16 h-elements
#pragma unroll
    for (int i = 0; i < 4; i++) {
        ushort4 o;
        o.x = f2bf(tile[rs + i * 4 + 0][c]); o.y = f2bf(tile[rs + i * 4 + 1][c]);
        o.z = f2bf(tile[rs + i * 4 + 2][c]); o.w = f2bf(tile[rs + i * 4 + 3][c]);
        *(ushort4*)(dst + (size_t)(c0 + c) * H_ + r0 + rs + i * 4) = o;
    }
}

// ---------- GEMM1: 64x64 tiles (576 blocks), ring-3 counted-vmcnt pipeline ----------
// head -> headh row-major f16; tail+b1 -> tailsw [32 jbg][36 chunk][8 u][16 row][8 e] f16
__global__ __launch_bounds__(256) void k_gemm1(
        const unsigned short* __restrict__ xb,     // [512][768] bf16
        const unsigned short* __restrict__ w1t,    // [4608][768] bf16
        const float* __restrict__ b1,              // [2304]
        unsigned short* __restrict__ headh,        // [512][2304] f16
        unsigned short* __restrict__ tailsw) {     // chunked tail, f16
    __shared__ __align__(16) unsigned short AB[3][4096];   // ring-3 {A 4KB | B 4KB}
    const int tid = threadIdx.x;
    const int l = tid & 63, w = tid >> 6;
    const int m0 = blockIdx.y * 64;
    const int n0 = blockIdx.x * 64;
    const int wr = (w >> 1) * 32, wc = (w & 1) * 32;
    const int lr = l & 15, lk = (l >> 4) * 8;
    f32x4 acc[2][2] = {};
    const int NKT = H_ / 32;   // 24

    auto stage = [&](int sbuf, int kt) {
        int row = tid >> 2, seg = (tid & 3) * 8;
        gload_lds16(xb  + (size_t)(m0 + row) * H_ + kt * 32 + seg, &AB[sbuf][tid * 8]);
        gload_lds16(w1t + (size_t)(n0 + row) * H_ + kt * 32 + seg, &AB[sbuf][2048 + tid * 8]);
    };

    stage(0, 0);
    stage(1, 1);

    for (int n = 0; n < NKT; ++n) {
        // outstanding at top: stage(n+1)[2] -> vmcnt(2) retires stage(n).
        asm volatile("s_waitcnt vmcnt(2)" ::: "memory");
        __builtin_amdgcn_s_barrier();
        // stage(n+2) after barrier (WAR-safe: buf readers = compute(n-1), whose
        // ds_reads retired before barrier(n)). Clamped dummy on tail iters.
        stage((n + 2) % 3, (n + 2 < NKT) ? (n + 2) : (NKT - 1));

        const unsigned short* Ab = &AB[n % 3][0];
        const unsigned short* Bb = &AB[n % 3][2048];
        bf16x8 af[2], bfr[2];
#pragma unroll
        for (int i = 0; i < 2; i++) af[i]  = *(const bf16x8*)(Ab + (wr + i * 16 + lr) * 32 + lk);
#pragma unroll
        for (int j = 0; j < 2; j++) bfr[j] = *(const bf16x8*)(Bb + (wc + j * 16 + lr) * 32 + lk);
#pragma unroll
        for (int i = 0; i < 2; i++)
#pragma unroll
            for (int j = 0; j < 2; j++)
                acc[i][j] = __builtin_amdgcn_mfma_f32_16x16x32_bf16(af[i], bfr[j], acc[i][j], 0, 0, 0);
    }

    const bool tailblk = (n0 >= K3);
    const int nloc = n0 - (tailblk ? K3 : 0);
    const int lv = (l >> 4) * 4;
    if (!tailblk) {
#pragma unroll
        for (int j = 0; j < 2; j++) {
            int c = nloc + wc + j * 16 + lr;
#pragma unroll
            for (int i = 0; i < 2; i++) {
                int mrow = m0 + wr + i * 16 + lv;
#pragma unroll
                for (int e = 0; e < 4; e++)
                    headh[(size_t)(mrow + e) * K3 + c] = f2h(acc[i][j][e]);
            }
        }
    } else {
#pragma unroll
        for (int j = 0; j < 2; j++) {
            int c = nloc + wc + j * 16 + lr;
            float bias = b1[c];
            int chunk = c >> 6, kin = c & 63, u = kin >> 3, ee = kin & 7;
#pragma unroll
            for (int i = 0; i < 2; i++) {
                int mrow = m0 + wr + i * 16 + lv;
#pragma unroll
                for (int e = 0; e < 4; e++) {
                    int r = mrow + e;                    // global row 0..511
                    int jbg = r >> 4, rr = r & 15;
                    size_t idx = (((size_t)(jbg * 36 + chunk) * 8 + u) * 16 + rr) * 8 + ee;
                    tailsw[idx] = f2h(acc[i][j][e] + bias);
                }
            }
        }
    }
}

// ---------- main pair kernel (R20-verbatim) ----------
__device__ __forceinline__ f16x8 form8t(uint4 hq, f16x8 t) {
    union { uint4 q; f16x8 v; } H;
    H.q = hq;
    f16x8 s = H.v + t;
    const f16x8 z = {0, 0, 0, 0, 0, 0, 0, 0};
    return __builtin_elementwise_max(s, z);
}

__global__ __launch_bounds__(256) void k_pair(
        const unsigned short* __restrict__ headh,  // [512][2304] f16
        const unsigned short* __restrict__ tailsw, // [32][36][8][16][8] f16
        const unsigned short* __restrict__ w2f,    // [72][6][64][8] f16 frag order
        const float* __restrict__ b2,              // [96]
        float* __restrict__ out) {                 // [4][128][128][96] fp32
    __shared__ __align__(16) unsigned short wlds[4][6144];   // 48KB W2 ring
    __shared__ __align__(16) unsigned short tlds[4][1024];   // 8KB tail ring

    const int tid = threadIdx.x;
    const int w = tid >> 6, l = tid & 63;
    const int lr = l & 15, lkq = l >> 4;
    const int lkoff = lkq * 8;
    const int jb = blockIdx.x;     // 0..7
    const int ig = blockIdx.y;     // 0..15
    const int b  = blockIdx.z;     // 0..3
    const int i0 = ig * 8;

    {   // start-stagger (measured neutral; kept from R20 baseline)
        int bid = jb + ig * 8 + b * 128;
        if ((bid >> 8) & 1) {
            __builtin_amdgcn_s_sleep(11);
            __builtin_amdgcn_s_sleep(11);
        }
    }

    const unsigned short* Hp   = headh + (size_t)(b * S_ + i0 + 2 * w) * K3;
    const unsigned short* Tsrc = tailsw + (size_t)(b * 8 + jb) * 36 * 1024;

    f32x4 acc[2][6] = {};
    float b2v[6];
#pragma unroll
    for (int f = 0; f < 6; f++) b2v[f] = b2[f * 16 + lr];

    auto stage = [&](int sbuf, int c) {
        const unsigned short* wsrc = w2f + (size_t)c * 6144;
#pragma unroll
        for (int i = 0; i < 3; ++i)
            gload_lds16(wsrc + i * 2048 + tid * 8, &wlds[sbuf][i * 2048 + tid * 8]);
        const unsigned short* tsrc = Tsrc + (size_t)c * 1024;
#pragma unroll
        for (int h = 0; h < 2; ++h)
            gload_lds16(tsrc + h * 512 + l * 8, &tlds[sbuf][h * 512 + l * 8]);
    };

    stage(0, 0);
    stage(1, 1);
    uint4 ha[2], hb[2];
#pragma unroll
    for (int kk = 0; kk < 2; kk++) {
        ha[kk] = *(const uint4*)(Hp + kk * 32 + lkoff);
        hb[kk] = *(const uint4*)(Hp + K3 + kk * 32 + lkoff);
    }

    for (int n = 0; n < NIT; ++n) {
        stage((n + 2) & 3, (n + 2 < NIT) ? (n + 2) : (NIT - 1));
        const int kn = ((n < NIT - 1) ? (n + 1) : n) * 64;
        uint4 han[2], hbn[2];
#pragma unroll
        for (int kk = 0; kk < 2; kk++) {
            han[kk] = *(const uint4*)(Hp + kn + kk * 32 + lkoff);
            hbn[kk] = *(const uint4*)(Hp + K3 + kn + kk * 32 + lkoff);
        }

        asm volatile("s_waitcnt vmcnt(9)" ::: "memory");
        __builtin_amdgcn_s_barrier();

        const unsigned short* Lb = &wlds[n & 3][0];
        const unsigned short* Tb = &tlds[n & 3][0];
        __builtin_amdgcn_s_setprio(1);
#pragma unroll
        for (int kk = 0; kk < 2; kk++) {
            f16x8 t8 = *(const f16x8*)(Tb + (kk * 4 + lkq) * 128 + lr * 8);
            f16x8 a0 = form8t(ha[kk], t8);
            f16x8 a1 = form8t(hb[kk], t8);
#pragma unroll
            for (int f = 0; f < 6; f++) {
                f16x8 bfr = *(const f16x8*)(Lb + kk * 3072 + f * 512 + l * 8);
                acc[0][f] = __builtin_amdgcn_mfma_f32_16x16x32_f16(a0, bfr, acc[0][f], 0, 0, 0);
                acc[1][f] = __builtin_amdgcn_mfma_f32_16x16x32_f16(a1, bfr, acc[1][f], 0, 0, 0);
            }
        }
        __builtin_amdgcn_s_setprio(0);
#pragma unroll
        for (int kk = 0; kk < 2; kk++) { ha[kk] = han[kk]; hb[kk] = hbn[kk]; }
    }

    float* O = out + (((size_t)(b * S_ + i0 + 2 * w)) * S_ + jb * 16) * NOUT;
#pragma unroll
    for (int q = 0; q < 2; q++)
#pragma unroll
        for (int f = 0; f < 6; f++)
#pragma unroll
            for (int e = 0; e < 4; e++) {
                int j = lkq * 4 + e;
                O[(size_t)q * S_ * NOUT + (size_t)j * NOUT + f * 16 + lr] = acc[q][f][e] + b2v[f];
            }
}

extern "C" void kernel_launch(void* const* d_in, const int* in_sizes, int n_in,
                              void* d_out, int out_size, void* d_ws, size_t ws_size,
                              hipStream_t stream) {
    const float* x  = (const float*)d_in[0];   // [4][128][768]
    const float* W1 = (const float*)d_in[1];   // [1536][2304]
    const float* b1 = (const float*)d_in[2];   // [2304]
    const float* W2 = (const float*)d_in[3];   // [2304][96]
    const float* b2 = (const float*)d_in[4];   // [96]
    float* out = (float*)d_out;

    char* ws = (char*)d_ws;
    unsigned short* xb     = (unsigned short*)(ws);              //  512*768   bf16
    unsigned short* w1t    = (unsigned short*)(ws +   786432);   // 4608*768   bf16
    unsigned short* w2f    = (unsigned short*)(ws +  7864320);   //  72*6*64*8 f16
    unsigned short* headh  = (unsigned short*)(ws +  8306688);   //  512*2304  f16
    unsigned short* tailsw = (unsigned short*)(ws + 10665984);   //  32*36*1024 f16 (2.36MB)
    // total ws use: 13,025,280 bytes

    hipLaunchKernelGGL(k_prep_w1, dim3(864), dim3(256), 0, stream, W1, w1t);
    hipLaunchKernelGGL(k_prep_xw2, dim3(492), dim3(256), 0, stream, x, xb, W2, w2f);
    hipLaunchKernelGGL(k_gemm1, dim3(72, 8), dim3(256), 0, stream,
                       xb, w1t, b1, headh, tailsw);
    hipLaunchKernelGGL(k_pair, dim3(8, 16, 4), dim3(256), 0, stream,
                       headh, tailsw, w2f, b2, out);
}

// Round 24
// 55.827 us; speedup vs baseline: 1.1169x; 1.0952x over previous
//
#include <hip/hip_runtime.h>
#include <hip/hip_bf16.h>

// Problem: B=4, S=128, H=768, OUT*TAG=96
// scores[b,i,j,o] = sum_k relu(head[b,i,k] + tail[b,j,k] + b1[k]) * W2[k,o] + b2[o]
// R23: k_pair = R18 ring-4 schedule, 2-chunk super-iterations: ONE barrier per
//      2 K-64 chunks, vmcnt(8) at barrier (keeps 8 in flight), vmcnt(14) mid.
//      gemm1 = R20 64x128 ring-3 (proven). prep = R20 fused single kernel.

typedef __bf16 bf16x8 __attribute__((ext_vector_type(8)));
typedef _Float16 f16x8 __attribute__((ext_vector_type(8)));
typedef float f32x4 __attribute__((ext_vector_type(4)));

#define S_   128
#define H_   768
#define K3   2304   // 3*H
#define NOUT 96
#define NIT  36     // K-step-64 chunks
#define NSI  18     // super-iterations (2 chunks each)

__device__ __forceinline__ unsigned short f2bf(float f) {
    union { __bf16 b; unsigned short u; } c;
    c.b = (__bf16)f;   // RNE
    return c.u;
}

__device__ __forceinline__ unsigned short f2h(float f) {
    union { _Float16 h; unsigned short u; } c;
    c.h = (_Float16)f;
    return c.u;
}

__device__ __forceinline__ void gload_lds16(const unsigned short* g, unsigned short* l) {
    __builtin_amdgcn_global_load_lds(
        (const __attribute__((address_space(1))) void*)g,
        (__attribute__((address_space(3))) void*)l,
        16, 0, 0);
}

// ---------- fused prep (R20): cvt_x | transpose W1 | pack W2 ----------
__global__ __launch_bounds__(256) void k_prep(
        const float* __restrict__ x, unsigned short* __restrict__ xb,
        const float* __restrict__ W1, unsigned short* __restrict__ w1t,
        const float* __restrict__ W2, unsigned short* __restrict__ w2f) {
    __shared__ float tile[32][33];
    const int bid = blockIdx.x, tid = threadIdx.x;
    if (bid < 384) {
        int t = bid * 256 + tid;
        float4 v = ((const float4*)x)[t];
        ushort4 o;
        o.x = f2bf(v.x); o.y = f2bf(v.y); o.z = f2bf(v.z); o.w = f2bf(v.w);
        ((ushort4*)xb)[t] = o;
    } else if (bid < 3840) {
        int idx = bid - 384;
        int bx = idx % 72, by = (idx / 72) % 24, bz = idx / 1728;   // 72 x 24 x 2
        const float* src = W1 + (size_t)bz * H_ * K3;
        unsigned short* dst = w1t + (size_t)bz * K3 * H_;
        int c0 = bx * 32, r0 = by * 32;
        int row = tid >> 3, c4 = (tid & 7) * 4;
        float4 v = *(const float4*)(src + (size_t)(r0 + row) * K3 + c0 + c4);
        tile[row][c4 + 0] = v.x; tile[row][c4 + 1] = v.y;
        tile[row][c4 + 2] = v.z; tile[row][c4 + 3] = v.w;
        __syncthreads();
        ushort4 o;
        o.x = f2bf(tile[c4 + 0][row]); o.y = f2bf(tile[c4 + 1][row]);
        o.z = f2bf(tile[c4 + 2][row]); o.w = f2bf(tile[c4 + 3][row]);
        *(ushort4*)(dst + (size_t)(c0 + row) * H_ + r0 + c4) = o;
    } else {
        int t = (bid - 3840) * 256 + tid;   // 27648 exact
        int l = t & 63, f = (t >> 6) % 6, kc = t / 384;
        int k0 = kc * 32 + (l >> 4) * 8;
        int o  = f * 16 + (l & 15);
        unsigned short v[8];
#pragma unroll
        for (int e = 0; e < 8; e++)
            v[e] = f2h(W2[(size_t)(k0 + e) * NOUT + o]);
        *(uint4*)(w2f + (size_t)t * 8) = *(const uint4*)v;
    }
}

// ---------- GEMM1 (R20-proven): 64x128 tiles (288 blocks), ring-3 pipeline ----------
// head -> headh row-major f16; tail+b1 -> tailsw [32 jbg][36 chunk][8 u][16 row][8 e] f16
__global__ __launch_bounds__(256) void k_gemm1(
        const unsigned short* __restrict__ xb,     // [512][768] bf16
        const unsigned short* __restrict__ w1t,    // [4608][768] bf16
        const float* __restrict__ b1,              // [2304]
        unsigned short* __restrict__ headh,        // [512][2304] f16
        unsigned short* __restrict__ tailsw) {     // chunked tail, f16
    __shared__ __align__(16) unsigned short AB[3][6144];   // ring-3 {A 4KB | B 8KB}
    const int tid = threadIdx.x;
    const int l = tid & 63, w = tid >> 6;
    const int m0 = blockIdx.y * 64;
    const int n0 = blockIdx.x * 128;
    const int wr = (w >> 1) * 32, wc = (w & 1) * 64;
    const int lr = l & 15, lk = (l >> 4) * 8;
    f32x4 acc[2][4] = {};
    const int NKT = H_ / 32;   // 24

    auto stage = [&](int sbuf, int kt) {
        {
            int row = tid >> 2, seg = (tid & 3) * 8;
            gload_lds16(xb + (size_t)(m0 + row) * H_ + kt * 32 + seg, &AB[sbuf][tid * 8]);
        }
#pragma unroll
        for (int p = 0; p < 2; ++p) {
            int idx = p * 256 + tid;
            int row = idx >> 2, seg = (idx & 3) * 8;
            gload_lds16(w1t + (size_t)(n0 + row) * H_ + kt * 32 + seg,
                        &AB[sbuf][2048 + idx * 8]);
        }
    };

    stage(0, 0);
    stage(1, 1);

    for (int n = 0; n < NKT; ++n) {
        asm volatile("s_waitcnt vmcnt(3)" ::: "memory");
        __builtin_amdgcn_s_barrier();
        stage((n + 2) % 3, (n + 2 < NKT) ? (n + 2) : (NKT - 1));

        const unsigned short* Ab = &AB[n % 3][0];
        const unsigned short* Bb = &AB[n % 3][2048];
        bf16x8 af[2], bfr[4];
#pragma unroll
        for (int i = 0; i < 2; i++) af[i]  = *(const bf16x8*)(Ab + (wr + i * 16 + lr) * 32 + lk);
#pragma unroll
        for (int j = 0; j < 4; j++) bfr[j] = *(const bf16x8*)(Bb + (wc + j * 16 + lr) * 32 + lk);
#pragma unroll
        for (int i = 0; i < 2; i++)
#pragma unroll
            for (int j = 0; j < 4; j++)
                acc[i][j] = __builtin_amdgcn_mfma_f32_16x16x32_bf16(af[i], bfr[j], acc[i][j], 0, 0, 0);
    }

    const bool tailblk = (n0 >= K3);
    const int nloc = n0 - (tailblk ? K3 : 0);
    const int lv = (l >> 4) * 4;
    if (!tailblk) {
#pragma unroll
        for (int j = 0; j < 4; j++) {
            int c = nloc + wc + j * 16 + lr;
#pragma unroll
            for (int i = 0; i < 2; i++) {
                int mrow = m0 + wr + i * 16 + lv;
#pragma unroll
                for (int e = 0; e < 4; e++)
                    headh[(size_t)(mrow + e) * K3 + c] = f2h(acc[i][j][e]);
            }
        }
    } else {
#pragma unroll
        for (int j = 0; j < 4; j++) {
            int c = nloc + wc + j * 16 + lr;
            float bias = b1[c];
            int chunk = c >> 6, kin = c & 63, u = kin >> 3, ee = kin & 7;
#pragma unroll
            for (int i = 0; i < 2; i++) {
                int mrow = m0 + wr + i * 16 + lv;
#pragma unroll
                for (int e = 0; e < 4; e++) {
                    int r = mrow + e;                    // global row 0..511
                    int jbg = r >> 4, rr = r & 15;
                    size_t idx = (((size_t)(jbg * 36 + chunk) * 8 + u) * 16 + rr) * 8 + ee;
                    tailsw[idx] = f2h(acc[i][j][e] + bias);
                }
            }
        }
    }
}

// ---------- main pair kernel: ring-4 + 2-chunk super-iterations ----------
// 256 thr (4 waves), tile 8i x 16j; wave w owns i = i0+2w, i0+2w+1.
// Super-iter m (chunks n=2m, n+1):
//   htO=ht(n+1)[4], htE=ht(n+2)[4] -> vmcnt(8) [retires stage(n),stage(n+1);
//   keeps htO+htE] -> s_barrier -> stage(n+2)[5], stage(n+3)[5] ->
//   compute(n) -> vmcnt(14) [retires htO only] -> compute(n+1).
// Ring-4 WAR safety: stage(n+2)/(n+3) clobber bufs whose readers (compute(n-2),
// compute(n-1)) completed their ds_reads before arriving at barrier(m).
__device__ __forceinline__ f16x8 form8t(uint4 hq, f16x8 t) {
    union { uint4 q; f16x8 v; } H;
    H.q = hq;
    f16x8 s = H.v + t;
    const f16x8 z = {0, 0, 0, 0, 0, 0, 0, 0};
    return __builtin_elementwise_max(s, z);
}

__global__ __launch_bounds__(256) void k_pair(
        const unsigned short* __restrict__ headh,  // [512][2304] f16
        const unsigned short* __restrict__ tailsw, // [32][36][8][16][8] f16
        const unsigned short* __restrict__ w2f,    // [72][6][64][8] f16 frag order
        const float* __restrict__ b2,              // [96]
        float* __restrict__ out) {                 // [4][128][128][96] fp32
    __shared__ __align__(16) unsigned short wlds[4][6144];   // 48KB W2 ring
    __shared__ __align__(16) unsigned short tlds[4][1024];   // 8KB tail ring

    const int tid = threadIdx.x;
    const int w = tid >> 6, l = tid & 63;
    const int lr = l & 15, lkq = l >> 4;
    const int lkoff = lkq * 8;
    const int jb = blockIdx.x;     // 0..7
    const int ig = blockIdx.y;     // 0..15
    const int b  = blockIdx.z;     // 0..3
    const int i0 = ig * 8;

    const unsigned short* Hp   = headh + (size_t)(b * S_ + i0 + 2 * w) * K3;
    const unsigned short* Tsrc = tailsw + (size_t)(b * 8 + jb) * 36 * 1024;

    f32x4 acc[2][6] = {};
    float b2v[6];
#pragma unroll
    for (int f = 0; f < 6; f++) b2v[f] = b2[f * 16 + lr];

    // stage K-64 chunk c into ring sbuf: W2 3 tid-ops + tail 2 l-ops (5 total)
    auto stage = [&](int sbuf, int c) {
        const unsigned short* wsrc = w2f + (size_t)c * 6144;
#pragma unroll
        for (int i = 0; i < 3; ++i)
            gload_lds16(wsrc + i * 2048 + tid * 8, &wlds[sbuf][i * 2048 + tid * 8]);
        const unsigned short* tsrc = Tsrc + (size_t)c * 1024;
#pragma unroll
        for (int h = 0; h < 2; ++h)
            gload_lds16(tsrc + h * 512 + l * 8, &tlds[sbuf][h * 512 + l * 8]);
    };

    stage(0, 0);
    stage(1, 1);
    // ht(0): 4 broadcast loads (current set)
    uint4 ha[2], hb[2];
#pragma unroll
    for (int kk = 0; kk < 2; kk++) {
        ha[kk] = *(const uint4*)(Hp + kk * 32 + lkoff);
        hb[kk] = *(const uint4*)(Hp + K3 + kk * 32 + lkoff);
    }

    for (int m = 0; m < NSI; ++m) {
        const int n = 2 * m;
        // htO = ht(n+1) [always valid: n+1 <= 35]
        uint4 hao[2], hbo[2];
        {
            const int kb = (n + 1) * 64;
#pragma unroll
            for (int kk = 0; kk < 2; kk++) {
                hao[kk] = *(const uint4*)(Hp + kb + kk * 32 + lkoff);
                hbo[kk] = *(const uint4*)(Hp + K3 + kb + kk * 32 + lkoff);
            }
        }
        // htE = ht(n+2) [clamped on last super-iter]
        uint4 hae[2], hbe[2];
        {
            const int kb = ((n + 2 < NIT) ? (n + 2) : (NIT - 1)) * 64;
#pragma unroll
            for (int kk = 0; kk < 2; kk++) {
                hae[kk] = *(const uint4*)(Hp + kb + kk * 32 + lkoff);
                hbe[kk] = *(const uint4*)(Hp + K3 + kb + kk * 32 + lkoff);
            }
        }

        // outstanding (old->new): stage(n)[5], stage(n+1)[5], [ht(n) if m==0],
        // htO[4], htE[4]. vmcnt(8) keeps htO+htE; retires both stages (+ht(n)).
        asm volatile("s_waitcnt vmcnt(8)" ::: "memory");
        __builtin_amdgcn_s_barrier();

        // depth-2 staging for the NEXT super-iter (clamped dummies on tail)
        stage((n + 2) & 3, (n + 2 < NIT) ? (n + 2) : (NIT - 1));
        stage((n + 3) & 3, (n + 3 < NIT) ? (n + 3) : (NIT - 1));

        // ---- compute(n): uses ha/hb + bufs n&3 ----
        {
            const unsigned short* Lb = &wlds[n & 3][0];
            const unsigned short* Tb = &tlds[n & 3][0];
            __builtin_amdgcn_s_setprio(1);
#pragma unroll
            for (int kk = 0; kk < 2; kk++) {
                f16x8 t8 = *(const f16x8*)(Tb + (kk * 4 + lkq) * 128 + lr * 8);
                f16x8 a0 = form8t(ha[kk], t8);
                f16x8 a1 = form8t(hb[kk], t8);
#pragma unroll
                for (int f = 0; f < 6; f++) {
                    f16x8 bfr = *(const f16x8*)(Lb + kk * 3072 + f * 512 + l * 8);
                    acc[0][f] = __builtin_amdgcn_mfma_f32_16x16x32_f16(a0, bfr, acc[0][f], 0, 0, 0);
                    acc[1][f] = __builtin_amdgcn_mfma_f32_16x16x32_f16(a1, bfr, acc[1][f], 0, 0, 0);
                }
            }
            __builtin_amdgcn_s_setprio(0);
        }

        // outstanding (old->new): htO[4], htE[4], stage(n+2)[5], stage(n+3)[5].
        // vmcnt(14) retires htO only (compute(n+1) needs it).
        asm volatile("s_waitcnt vmcnt(14)" ::: "memory");

        // ---- compute(n+1): uses hao/hbo + bufs (n+1)&3 ----
        {
            const unsigned short* Lb = &wlds[(n + 1) & 3][0];
            const unsigned short* Tb = &tlds[(n + 1) & 3][0];
            __builtin_amdgcn_s_setprio(1);
#pragma unroll
            for (int kk = 0; kk < 2; kk++) {
                f16x8 t8 = *(const f16x8*)(Tb + (kk * 4 + lkq) * 128 + lr * 8);
                f16x8 a0 = form8t(hao[kk], t8);
                f16x8 a1 = form8t(hbo[kk], t8);
#pragma unroll
                for (int f = 0; f < 6; f++) {
                    f16x8 bfr = *(const f16x8*)(Lb + kk * 3072 + f * 512 + l * 8);
                    acc[0][f] = __builtin_amdgcn_mfma_f32_16x16x32_f16(a0, bfr, acc[0][f], 0, 0, 0);
                    acc[1][f] = __builtin_amdgcn_mfma_f32_16x16x32_f16(a1, bfr, acc[1][f], 0, 0, 0);
                }
            }
            __builtin_amdgcn_s_setprio(0);
        }

        // rotate: current <- htE
#pragma unroll
        for (int kk = 0; kk < 2; kk++) { ha[kk] = hae[kk]; hb[kk] = hbe[kk]; }
    }

    float* O = out + (((size_t)(b * S_ + i0 + 2 * w)) * S_ + jb * 16) * NOUT;
#pragma unroll
    for (int q = 0; q < 2; q++)
#pragma unroll
        for (int f = 0; f < 6; f++)
#pragma unroll
            for (int e = 0; e < 4; e++) {
                int j = lkq * 4 + e;
                O[(size_t)q * S_ * NOUT + (size_t)j * NOUT + f * 16 + lr] = acc[q][f][e] + b2v[f];
            }
}

extern "C" void kernel_launch(void* const* d_in, const int* in_sizes, int n_in,
                              void* d_out, int out_size, void* d_ws, size_t ws_size,
                              hipStream_t stream) {
    const float* x  = (const float*)d_in[0];   // [4][128][768]
    const float* W1 = (const float*)d_in[1];   // [1536][2304]
    const float* b1 = (const float*)d_in[2];   // [2304]
    const float* W2 = (const float*)d_in[3];   // [2304][96]
    const float* b2 = (const float*)d_in[4];   // [96]
    float* out = (float*)d_out;

    char* ws = (char*)d_ws;
    unsigned short* xb     = (unsigned short*)(ws);              //  512*768   bf16
    unsigned short* w1t    = (unsigned short*)(ws +   786432);   // 4608*768   bf16
    unsigned short* w2f    = (unsigned short*)(ws +  7864320);   //  72*6*64*8 f16
    unsigned short* headh  = (unsigned short*)(ws +  8306688);   //  512*2304  f16
    unsigned short* tailsw = (unsigned short*)(ws + 10665984);   //  32*36*1024 f16 (2.36MB)
    // total ws use: 13,025,280 bytes

    hipLaunchKernelGGL(k_prep, dim3(3948), dim3(256), 0, stream,
                       x, xb, W1, w1t, W2, w2f);
    hipLaunchKernelGGL(k_gemm1, dim3(36, 8), dim3(256), 0, stream,
                       xb, w1t, b1, headh, tailsw);
    hipLaunchKernelGGL(k_pair, dim3(8, 16, 4), dim3(256), 0, stream,
                       headh, tailsw, w2f, b2, out);
}